// Round 17
// baseline (117.418 us; speedup 1.0000x reference)
//
#include <hip/hip_runtime.h>
#include <hip/hip_bf16.h>

// ConvEGNN3 round 17: dual-node ILP on the r15 register-chained structure.
// r16 proved occupancy is stuck at 2 waves/SIMD (register budget) and the
// kernel is latency-bound (no pipe >40%). Second independent chain per wave
// fills the bubbles. Fits NOW (unlike r5/r7) because r15+cvt_pk cut live-V
// to 84: dual adds ~35 V (prefetch+transients) + 16 A (acc) -> V~119<=128,
// A=96<=128 at (256,2). Shared per-pair: a1/f2/f3 frags, w1l, wx2, c2v/c3v.
// Scratch gains a parity dim (+8KB -> ~57KB LDS, still 2 blocks/CU).

typedef __attribute__((ext_vector_type(8))) short short8;
typedef __attribute__((ext_vector_type(4))) float f32x4;
typedef __attribute__((ext_vector_type(2))) float f32x2;
typedef __attribute__((ext_vector_type(2))) unsigned int u32x2;
typedef __attribute__((ext_vector_type(4))) unsigned int u32x4;

#define NODES 16384
#define NPB   16
#define NBLK  (NODES / NPB)

#define MFMA16(a, b, c) __builtin_amdgcn_mfma_f32_16x16x32_bf16((a), (b), (c), 0, 0, 0)

__device__ __forceinline__ unsigned short f2bf(float f) {
  unsigned int u = __float_as_uint(f);
  u += 0x7FFFu + ((u >> 16) & 1u);
  return (unsigned short)(u >> 16);
}
__device__ __forceinline__ unsigned int pk2(float lo, float hi) {
  unsigned int r;
  asm("v_cvt_pk_bf16_f32 %0, %1, %2" : "=v"(r) : "v"(lo), "v"(hi));
  return r;
}
__device__ __forceinline__ float bfl(unsigned int u) { return __uint_as_float(u << 16); }
__device__ __forceinline__ float bfh(unsigned int u) { return __uint_as_float(u & 0xFFFF0000u); }
__device__ __forceinline__ float silu_f(float x) {
  return x * __builtin_amdgcn_rcpf(1.f + __expf(-x));
}
__device__ __forceinline__ f32x4 silu4(f32x4 x) {
  f32x4 r; r[0]=silu_f(x[0]); r[1]=silu_f(x[1]); r[2]=silu_f(x[2]); r[3]=silu_f(x[3]); return r;
}
__device__ __forceinline__ short8 packb(f32x4 a, f32x4 b) {
  u32x4 t;
  t[0] = pk2(a[0], a[1]); t[1] = pk2(a[2], a[3]);
  t[2] = pk2(b[0], b[1]); t[3] = pk2(b[2], b[3]);
  return __builtin_bit_cast(short8, t);
}
// standard k-order fragment: k = k0 + m
__device__ __forceinline__ short8 ldfragT(const float* __restrict__ W, int k0, int col) {
  short8 r;
  #pragma unroll
  for (int m = 0; m < 8; m++) r[m] = (short)f2bf(W[(k0 + m) * 64 + col]);
  return r;
}
// D-layout-matched k-perm fragment: k = 32*kk + (m<4 ? 4*lg+m : 16+4*lg+(m-4))
__device__ __forceinline__ short8 ldfragP(const float* __restrict__ W, int kk, int lg, int col) {
  short8 r;
  #pragma unroll
  for (int m = 0; m < 8; m++) {
    const int k = 32 * kk + ((m < 4) ? (4 * lg + m) : (16 + 4 * lg + (m - 4)));
    r[m] = (short)f2bf(W[k * 64 + col]);
  }
  return r;
}

__global__ __launch_bounds__(256, 2) void egnn_mfma(
    const float* __restrict__ ped, const float* __restrict__ h_st,
    const float* __restrict__ h_neigh, const float* __restrict__ rela,
    const unsigned char* __restrict__ mask8,
    const float* __restrict__ We1, const float* __restrict__ be1,
    const float* __restrict__ We2, const float* __restrict__ be2,
    const float* __restrict__ Wx1, const float* __restrict__ bx1,
    const float* __restrict__ Wx2, const float* __restrict__ bx2,
    const float* __restrict__ Wh1, const float* __restrict__ bh1,
    const float* __restrict__ Wh2, const float* __restrict__ bh2,
    float* __restrict__ out)
{
  __shared__ __align__(16) float s_hst[16][64];
  __shared__ __align__(16) float s_u[16][64];
  __shared__ __align__(16) float s_miw[4][16][64];
  __shared__ __align__(16) unsigned int s_scr[4][2][2][64][4];  // [wave][parity][k-half][lane][word]
  __shared__ __align__(16) short8 s_af[16][64];   // permuted a2/a3 fragments
  __shared__ float s_w1l[64];
  __shared__ float s_wx2[64];
  __shared__ float s_aggx[4][16], s_aggy[4][16], s_nn[4][16];
  __shared__ int s_flags[2];

  const int t  = threadIdx.x;
  const int l  = t & 63;
  const int w  = t >> 6;
  const int lg = l >> 4;
  const int jl = l & 15;
  const int base = blockIdx.x * NPB;

  if (t == 0) { s_flags[0] = 1; s_flags[1] = 1; }
  __syncthreads();
  {
    const unsigned int* mw = (const unsigned int*)mask8;
    unsigned int iok = 1, fok = 1;
    #pragma unroll
    for (int q = 0; q < 4; q++) {
      unsigned int v = mw[t * 4 + q];
      if (v > 1u) iok = 0;
      if (v != 0u && v != 0x3F800000u) fok = 0;
    }
    if (!iok) atomicAnd(&s_flags[0], 0);
    if (!fok) atomicAnd(&s_flags[1], 0);
  }
  {
    const f32x4* src = (const f32x4*)(h_st + (size_t)base * 64);
    f32x4* dst = (f32x4*)&s_hst[0][0];
    dst[t] = src[t];
    if (t < 64)       s_w1l[t] = We1[128 * 64 + t];
    else if (t < 128) s_wx2[t - 64] = Wx2[t - 64];
  }
  // stage permuted a2/a3 fragments
  #pragma unroll
  for (int ci = 0; ci < 4; ci++) {
    const int c  = 4 * w + ci;
    const int g  = c >> 3, mt = (c >> 1) & 3, kk = c & 1;
    const float* W = g ? Wx1 : We2;
    s_af[c][l] = ldfragP(W, kk, lg, 16 * mt + jl);
  }
  __syncthreads();
  const int mode = s_flags[0] ? 0 : (s_flags[1] ? 1 : 2);

  auto ldmask = [&](size_t idx) -> float {
    if (mode == 0)      return (((const int*)mask8)[idx] != 0) ? 1.f : 0.f;
    else if (mode == 1) return (((const float*)mask8)[idx] != 0.f) ? 1.f : 0.f;
    else                return (mask8[idx] != 0) ? 1.f : 0.f;
  };

  const int sc_lgp_e = (lg >> 1);
  const int sc_m0    = 2 * (lg & 1);

  // ---- U = be1 + h_st @ We1[0:64] ----
  {
    f32x4 uacc = {0.f, 0.f, 0.f, 0.f};
    #pragma unroll
    for (int kk = 0; kk < 2; kk++) {
      short8 au = ldfragT(We1, 8 * lg + 32 * kk, 16 * w + jl);
      f32x4 q0 = *(const f32x4*)&s_hst[jl][8 * lg + 32 * kk];
      f32x4 q1 = *(const f32x4*)&s_hst[jl][8 * lg + 32 * kk + 4];
      uacc = MFMA16(au, packb(q0, q1), uacc);
    }
    f32x4 b1v = *(const f32x4*)(be1 + 16 * w + 4 * lg);
    *(f32x4*)&s_u[jl][16 * w + 4 * lg] = uacc + b1v;
  }

  // ---- a1 in registers/AGPR ----
  short8 a1[4][2];
  #pragma unroll
  for (int mt = 0; mt < 4; mt++)
    #pragma unroll
    for (int kk = 0; kk < 2; kk++)
      a1[mt][kk] = ldfragT(We1 + 64 * 64, 8 * lg + 32 * kk, 16 * mt + jl);

  // ---- be2/bx1 acc-inits in registers (MFMA C-operand) ----
  f32x4 c2v[4], c3v[4];
  #pragma unroll
  for (int ht = 0; ht < 4; ht++) {
    c2v[ht] = *(const f32x4*)(be2 + 16 * ht + 4 * lg);
    c3v[ht] = *(const f32x4*)(bx1 + 16 * ht + 4 * lg);
  }
  const float bx2s = bx2[0];

  // ---- prefetch pair 0 ----
  const float* hn_lane = h_neigh + ((size_t)base * 64 + 16 * w + jl) * 64 + 8 * lg;
  const size_t ro = (size_t)base * 64 + 16 * w + jl;
  f32x4 pA0, pA1, pA2, pA3, pB0, pB1, pB2, pB3;
  f32x2 prA, prB; float pmA, pmB;
  {
    const float* qA = hn_lane;
    const float* qB = hn_lane + 4096;
    pA0 = *(const f32x4*)(qA + 0);  pA1 = *(const f32x4*)(qA + 4);
    pA2 = *(const f32x4*)(qA + 32); pA3 = *(const f32x4*)(qA + 36);
    pB0 = *(const f32x4*)(qB + 0);  pB1 = *(const f32x4*)(qB + 4);
    pB2 = *(const f32x4*)(qB + 32); pB3 = *(const f32x4*)(qB + 36);
    prA = *(const f32x2*)(rela + ro * 6);
    prB = *(const f32x2*)(rela + (ro + 64) * 6);
    pmA = ldmask(ro);
    pmB = ldmask(ro + 64);
  }
  __syncthreads();  // s_u + s_af ready

  // =========================== main loop (2 nodes/iter) ===========================
  #pragma unroll 1
  for (int np = 0; np < NPB / 2; np++) {
    const int nA = 2 * np, nB = nA + 1;
    // pack FIRST so pf regs die before next prefetch issues
    const short8 b1A0 = packb(pA0, pA1), b1A1 = packb(pA2, pA3);
    const short8 b1B0 = packb(pB0, pB1), b1B1 = packb(pB2, pB3);
    const f32x2 rrA = prA, rrB = prB;
    const float mfA = pmA, mfB = pmB;
    if (np < NPB / 2 - 1) {
      const float* qA = hn_lane + (size_t)(nA + 2) * 4096;
      const float* qB = hn_lane + (size_t)(nB + 2) * 4096;
      pA0 = *(const f32x4*)(qA + 0);  pA1 = *(const f32x4*)(qA + 4);
      pA2 = *(const f32x4*)(qA + 32); pA3 = *(const f32x4*)(qA + 36);
      pB0 = *(const f32x4*)(qB + 0);  pB1 = *(const f32x4*)(qB + 4);
      pB2 = *(const f32x4*)(qB + 32); pB3 = *(const f32x4*)(qB + 36);
      prA = *(const f32x2*)(rela + (ro + (size_t)(nA + 2) * 64) * 6);
      prB = *(const f32x2*)(rela + (ro + (size_t)(nB + 2) * 64) * 6);
      pmA = ldmask(ro + (size_t)(nA + 2) * 64);
      pmB = ldmask(ro + (size_t)(nB + 2) * 64);
    }
    const float dA = sqrtf(rrA[0] * rrA[0] + rrA[1] * rrA[1]);
    const float dB = sqrtf(rrB[0] * rrB[0] + rrB[1] * rrB[1]);

    float msA = mfA, msB = mfB;
    msA += __shfl_xor(msA, 1, 64); msB += __shfl_xor(msB, 1, 64);
    msA += __shfl_xor(msA, 2, 64); msB += __shfl_xor(msB, 2, 64);
    msA += __shfl_xor(msA, 4, 64); msB += __shfl_xor(msB, 4, 64);
    msA += __shfl_xor(msA, 8, 64); msB += __shfl_xor(msB, 8, 64);
    if (l == 0) { s_nn[w][nA] = msA; s_nn[w][nB] = msB; }

    // ---- GEMM1 (shared a1/w1l/s_u reads) ----
    f32x4 aA[4], aB[4];
    #pragma unroll
    for (int ht = 0; ht < 4; ht++) {
      const f32x4 wl = *(const f32x4*)&s_w1l[16 * ht + 4 * lg];
      aA[ht] = *(const f32x4*)&s_u[nA][16 * ht + 4 * lg] + dA * wl;
      aB[ht] = *(const f32x4*)&s_u[nB][16 * ht + 4 * lg] + dB * wl;
      aA[ht] = MFMA16(a1[ht][0], b1A0, aA[ht]);
      aB[ht] = MFMA16(a1[ht][0], b1B0, aB[ht]);
      aA[ht] = MFMA16(a1[ht][1], b1A1, aA[ht]);
      aB[ht] = MFMA16(a1[ht][1], b1B1, aB[ht]);
    }
    // E -> register B-fragments (perm handled by a2); temps die immediately
    short8 b2A0, b2A1, b2B0, b2B1;
    {
      f32x4 s0 = silu4(aA[0]), s1 = silu4(aA[1]), s2 = silu4(aA[2]), s3 = silu4(aA[3]);
      b2A0 = packb(s0, s1); b2A1 = packb(s2, s3);
      s0 = silu4(aB[0]); s1 = silu4(aB[1]); s2 = silu4(aB[2]); s3 = silu4(aB[3]);
      b2B0 = packb(s0, s1); b2B1 = packb(s2, s3);
    }

    // ---- GEMM2 (f2 loaded once, both chains) ----
    #pragma unroll
    for (int ht = 0; ht < 4; ht++) {
      const short8 f2k0 = s_af[2 * ht][l];
      const short8 f2k1 = s_af[2 * ht + 1][l];
      aA[ht] = MFMA16(f2k0, b2A0, c2v[ht]);
      aB[ht] = MFMA16(f2k0, b2B0, c2v[ht]);
      aA[ht] = MFMA16(f2k1, b2A1, aA[ht]);
      aB[ht] = MFMA16(f2k1, b2B1, aB[ht]);
    }
    // M: silu*mask, pack once (shared by scratch write and b3), parity scratch
    short8 b3A0, b3A1, b3B0, b3B1;
    {
      u32x2 wv;
      f32x4 m0 = silu4(aA[0]) * mfA, m1 = silu4(aA[1]) * mfA;
      f32x4 m2 = silu4(aA[2]) * mfA, m3 = silu4(aA[3]) * mfA;
      u32x4 t0; t0[0] = pk2(m0[0], m0[1]); t0[1] = pk2(m0[2], m0[3]);
      t0[2] = pk2(m1[0], m1[1]); t0[3] = pk2(m1[2], m1[3]);
      u32x4 t1; t1[0] = pk2(m2[0], m2[1]); t1[1] = pk2(m2[2], m2[3]);
      t1[2] = pk2(m3[0], m3[1]); t1[3] = pk2(m3[2], m3[3]);
      wv[0] = t0[0]; wv[1] = t0[1];
      *(u32x2*)&s_scr[w][0][(0 + lg) >> 3][((0 + sc_lgp_e) & 3) * 16 + jl][sc_m0] = wv;
      wv[0] = t0[2]; wv[1] = t0[3];
      *(u32x2*)&s_scr[w][0][(4 + lg) >> 3][((2 + sc_lgp_e) & 3) * 16 + jl][sc_m0] = wv;
      wv[0] = t1[0]; wv[1] = t1[1];
      *(u32x2*)&s_scr[w][0][(8 + lg) >> 3][((4 + sc_lgp_e) & 3) * 16 + jl][sc_m0] = wv;
      wv[0] = t1[2]; wv[1] = t1[3];
      *(u32x2*)&s_scr[w][0][(12 + lg) >> 3][((6 + sc_lgp_e) & 3) * 16 + jl][sc_m0] = wv;
      b3A0 = __builtin_bit_cast(short8, t0);
      b3A1 = __builtin_bit_cast(short8, t1);
      m0 = silu4(aB[0]) * mfB; m1 = silu4(aB[1]) * mfB;
      m2 = silu4(aB[2]) * mfB; m3 = silu4(aB[3]) * mfB;
      t0[0] = pk2(m0[0], m0[1]); t0[1] = pk2(m0[2], m0[3]);
      t0[2] = pk2(m1[0], m1[1]); t0[3] = pk2(m1[2], m1[3]);
      t1[0] = pk2(m2[0], m2[1]); t1[1] = pk2(m2[2], m2[3]);
      t1[2] = pk2(m3[0], m3[1]); t1[3] = pk2(m3[2], m3[3]);
      wv[0] = t0[0]; wv[1] = t0[1];
      *(u32x2*)&s_scr[w][1][(0 + lg) >> 3][((0 + sc_lgp_e) & 3) * 16 + jl][sc_m0] = wv;
      wv[0] = t0[2]; wv[1] = t0[3];
      *(u32x2*)&s_scr[w][1][(4 + lg) >> 3][((2 + sc_lgp_e) & 3) * 16 + jl][sc_m0] = wv;
      wv[0] = t1[0]; wv[1] = t1[1];
      *(u32x2*)&s_scr[w][1][(8 + lg) >> 3][((4 + sc_lgp_e) & 3) * 16 + jl][sc_m0] = wv;
      wv[0] = t1[2]; wv[1] = t1[3];
      *(u32x2*)&s_scr[w][1][(12 + lg) >> 3][((6 + sc_lgp_e) & 3) * 16 + jl][sc_m0] = wv;
      b3B0 = __builtin_bit_cast(short8, t0);
      b3B1 = __builtin_bit_cast(short8, t1);
    }

    // ---- GEMM3 (f3 loaded once, both chains) ----
    #pragma unroll
    for (int ht = 0; ht < 4; ht++) {
      const short8 f3k0 = s_af[8 + 2 * ht][l];
      const short8 f3k1 = s_af[8 + 2 * ht + 1][l];
      aA[ht] = MFMA16(f3k0, b3A0, c3v[ht]);
      aB[ht] = MFMA16(f3k0, b3B0, c3v[ht]);
      aA[ht] = MFMA16(f3k1, b3A1, aA[ht]);
      aB[ht] = MFMA16(f3k1, b3B1, aB[ht]);
    }

    // ---- m_i partials (both parities; overlaps GEMM3 MFMA latency) ----
    {
      const int hw = l & 31, jh = l >> 5;
      const int half = hw >> 4;
      const int lgp  = (hw & 15) >> 2;
      const int m0   = hw & 3;
      const int rot  = hw >> 2;
      float peA = 0.f, poA = 0.f, peB = 0.f, poB = 0.f;
      #pragma unroll
      for (int c = 0; c < 8; c++) {
        const int j = 8 * jh + ((c + rot) & 7);
        unsigned int vA = s_scr[w][0][half][lgp * 16 + j][m0];
        unsigned int vB = s_scr[w][1][half][lgp * 16 + j][m0];
        peA += bfl(vA); poA += bfh(vA);
        peB += bfl(vB); poB += bfh(vB);
      }
      peA += __shfl_xor(peA, 32, 64); poA += __shfl_xor(poA, 32, 64);
      peB += __shfl_xor(peB, 32, 64); poB += __shfl_xor(poB, 32, 64);
      if (l < 32) {
        f32x2 vA; vA[0] = peA; vA[1] = poA;
        f32x2 vB; vB[0] = peB; vB[1] = poB;
        *(f32x2*)&s_miw[w][nA][2 * hw] = vA;
        *(f32x2*)&s_miw[w][nB][2 * hw] = vB;
      }
    }

    // ---- gates ----
    float ggA = 0.f, ggB = 0.f;
    #pragma unroll
    for (int ht = 0; ht < 4; ht++) {
      const f32x4 wx = *(const f32x4*)&s_wx2[16 * ht + 4 * lg];
      f32x4 gA = silu4(aA[ht]);
      f32x4 gB = silu4(aB[ht]);
      ggA += gA[0] * wx[0] + gA[1] * wx[1] + gA[2] * wx[2] + gA[3] * wx[3];
      ggB += gB[0] * wx[0] + gB[1] * wx[1] + gB[2] * wx[2] + gB[3] * wx[3];
    }
    ggA += __shfl_xor(ggA, 16, 64); ggB += __shfl_xor(ggB, 16, 64);
    ggA += __shfl_xor(ggA, 32, 64); ggB += __shfl_xor(ggB, 32, 64);
    const float gateA = ggA + bx2s;
    const float gateB = ggB + bx2s;

    float axA = rrA[0] * gateA, ayA = rrA[1] * gateA;
    float axB = rrB[0] * gateB, ayB = rrB[1] * gateB;
    axA += __shfl_xor(axA, 1, 64); ayA += __shfl_xor(ayA, 1, 64);
    axB += __shfl_xor(axB, 1, 64); ayB += __shfl_xor(ayB, 1, 64);
    axA += __shfl_xor(axA, 2, 64); ayA += __shfl_xor(ayA, 2, 64);
    axB += __shfl_xor(axB, 2, 64); ayB += __shfl_xor(ayB, 2, 64);
    axA += __shfl_xor(axA, 4, 64); ayA += __shfl_xor(ayA, 4, 64);
    axB += __shfl_xor(axB, 4, 64); ayB += __shfl_xor(ayB, 4, 64);
    axA += __shfl_xor(axA, 8, 64); ayA += __shfl_xor(ayA, 8, 64);
    axB += __shfl_xor(axB, 8, 64); ayB += __shfl_xor(ayB, 8, 64);
    if (l == 0) {
      s_aggx[w][nA] = axA; s_aggy[w][nA] = ayA;
      s_aggx[w][nB] = axB; s_aggy[w][nB] = ayB;
    }
  }
  __syncthreads();

  // ---- x_new ----
  if (t < 32) {
    const int node = t >> 1, c = t & 1;
    const float nn = s_nn[0][node] + s_nn[1][node] + s_nn[2][node] + s_nn[3][node];
    const float ag = (c ? (s_aggy[0][node] + s_aggy[1][node] + s_aggy[2][node] + s_aggy[3][node])
                        : (s_aggx[0][node] + s_aggx[1][node] + s_aggx[2][node] + s_aggx[3][node]));
    out[(size_t)(base + node) * 2 + c] =
        ped[(size_t)(base + node) * 2 + c] + ag / (nn + 1e-6f);
  }

  // ---- f_h batched over 16 nodes (r15 path; parity-0 scratch) ----
  {
    f32x4 hacc = *(const f32x4*)(bh1 + 16 * w + 4 * lg);
    #pragma unroll
    for (int kk = 0; kk < 4; kk++) {
      short8 ah = ldfragT(Wh1, 8 * lg + 32 * kk, 16 * w + jl);
      f32x4 q0, q1;
      if (kk < 2) {
        q0 = *(const f32x4*)&s_hst[jl][8 * lg + 32 * kk];
        q1 = *(const f32x4*)&s_hst[jl][8 * lg + 32 * kk + 4];
      } else {
        const int off = 8 * lg + 32 * (kk - 2);
        q0 = *(const f32x4*)&s_miw[0][jl][off]     + *(const f32x4*)&s_miw[1][jl][off]
           + *(const f32x4*)&s_miw[2][jl][off]     + *(const f32x4*)&s_miw[3][jl][off];
        q1 = *(const f32x4*)&s_miw[0][jl][off + 4] + *(const f32x4*)&s_miw[1][jl][off + 4]
           + *(const f32x4*)&s_miw[2][jl][off + 4] + *(const f32x4*)&s_miw[3][jl][off + 4];
      }
      hacc = MFMA16(ah, packb(q0, q1), hacc);
    }
    f32x4 h1 = silu4(hacc);
    u32x2 wv; wv[0] = pk2(h1[0], h1[1]); wv[1] = pk2(h1[2], h1[3]);
    const int half = (4 * w + lg) >> 3;
    const int lgp  = (2 * w + sc_lgp_e) & 3;
    *(u32x2*)&s_scr[0][0][half][lgp * 16 + jl][sc_m0] = wv;
  }
  __syncthreads();
  {
    short8 hb0 = *(const short8*)&s_scr[0][0][0][l][0];
    short8 hb1 = *(const short8*)&s_scr[0][0][1][l][0];
    short8 aw0 = ldfragT(Wh2, 8 * lg,      16 * w + jl);
    short8 aw1 = ldfragT(Wh2, 8 * lg + 32, 16 * w + jl);
    f32x4 oacc = *(const f32x4*)(bh2 + 16 * w + 4 * lg);
    oacc = MFMA16(aw0, hb0, oacc);
    oacc = MFMA16(aw1, hb1, oacc);
    f32x4 res = oacc + *(const f32x4*)&s_hst[jl][16 * w + 4 * lg];
    *(f32x4*)(out + 32768 + (size_t)(base + jl) * 64 + 16 * w + 4 * lg) = res;
  }
}

extern "C" void kernel_launch(void* const* d_in, const int* in_sizes, int n_in,
                              void* d_out, int out_size, void* d_ws, size_t ws_size,
                              hipStream_t stream) {
  (void)in_sizes; (void)n_in; (void)out_size; (void)d_ws; (void)ws_size;
  const float* ped     = (const float*)d_in[0];
  const float* h_st    = (const float*)d_in[1];
  const float* h_neigh = (const float*)d_in[2];
  const float* rela    = (const float*)d_in[3];
  const unsigned char* mask = (const unsigned char*)d_in[4];
  const float* We1 = (const float*)d_in[5];  const float* be1 = (const float*)d_in[6];
  const float* We2 = (const float*)d_in[7];  const float* be2 = (const float*)d_in[8];
  const float* Wx1 = (const float*)d_in[9];  const float* bx1 = (const float*)d_in[10];
  const float* Wx2 = (const float*)d_in[11]; const float* bx2 = (const float*)d_in[12];
  const float* Wh1 = (const float*)d_in[13]; const float* bh1 = (const float*)d_in[14];
  const float* Wh2 = (const float*)d_in[15]; const float* bh2 = (const float*)d_in[16];

  hipLaunchKernelGGL(egnn_mfma, dim3(NBLK), dim3(256), 0, stream,
                     ped, h_st, h_neigh, rela, mask,
                     We1, be1, We2, be2, Wx1, bx1, Wx2, bx2,
                     Wh1, bh1, Wh2, bh2, (float*)d_out);
}

// Round 18
// 111.855 us; speedup vs baseline: 1.0497x; 1.0497x over previous
//
#include <hip/hip_runtime.h>
#include <hip/hip_bf16.h>

// ConvEGNN3 FINAL (round 18 = round 10 verbatim, best measured: 111.3us).
// 9x faster than the fp32 baseline (998us), 1.6x faster than first MFMA (182us).
// Structure: per-node chained 64x64 GEMMs in transposed (hidden x neighbor)
// MFMA layout; 4 waves x 16 j; conflict-free fragment-scratch; cvt_pk packs;
// fast silu (exp+rcp); a2/a3 weight frags JIT from LDS; 72 VGPR, no spill.
// Plateau evidence (r10-r17): occupancy +50% null, LDS-diet null, register-
// chained GEMMs null, dual-node ILP (no spill) null -> composite latency
// limit at 2 waves/SIMD; no pipe >40%.

typedef __attribute__((ext_vector_type(8))) short short8;
typedef __attribute__((ext_vector_type(4))) float f32x4;
typedef __attribute__((ext_vector_type(2))) float f32x2;
typedef __attribute__((ext_vector_type(2))) unsigned int u32x2;
typedef __attribute__((ext_vector_type(4))) unsigned int u32x4;

#define NODES 16384
#define NPB   16
#define NBLK  (NODES / NPB)

#define MFMA16(a, b, c) __builtin_amdgcn_mfma_f32_16x16x32_bf16((a), (b), (c), 0, 0, 0)

// exact RNE scalar (prologue weight-fragment loads only)
__device__ __forceinline__ unsigned short f2bf(float f) {
  unsigned int u = __float_as_uint(f);
  u += 0x7FFFu + ((u >> 16) & 1u);
  return (unsigned short)(u >> 16);
}
// 1-op pack: dst.lo16 = bf16(lo), dst.hi16 = bf16(hi)  (RNE)
__device__ __forceinline__ unsigned int pk2(float lo, float hi) {
  unsigned int r;
  asm("v_cvt_pk_bf16_f32 %0, %1, %2" : "=v"(r) : "v"(lo), "v"(hi));
  return r;
}
__device__ __forceinline__ float bfl(unsigned int u) { return __uint_as_float(u << 16); }
__device__ __forceinline__ float bfh(unsigned int u) { return __uint_as_float(u & 0xFFFF0000u); }
__device__ __forceinline__ float silu_f(float x) {
  return x * __builtin_amdgcn_rcpf(1.f + __expf(-x));
}
__device__ __forceinline__ f32x4 silu4(f32x4 x) {
  f32x4 r; r[0]=silu_f(x[0]); r[1]=silu_f(x[1]); r[2]=silu_f(x[2]); r[3]=silu_f(x[3]); return r;
}
__device__ __forceinline__ short8 packb(f32x4 a, f32x4 b) {
  u32x4 t;
  t[0] = pk2(a[0], a[1]); t[1] = pk2(a[2], a[3]);
  t[2] = pk2(b[0], b[1]); t[3] = pk2(b[2], b[3]);
  return __builtin_bit_cast(short8, t);
}
__device__ __forceinline__ short8 ldfragT(const float* __restrict__ W, int k0, int col) {
  short8 r;
  #pragma unroll
  for (int m = 0; m < 8; m++) r[m] = (short)f2bf(W[(k0 + m) * 64 + col]);
  return r;
}

__global__ __launch_bounds__(256, 3) void egnn_mfma(
    const float* __restrict__ ped, const float* __restrict__ h_st,
    const float* __restrict__ h_neigh, const float* __restrict__ rela,
    const unsigned char* __restrict__ mask8,
    const float* __restrict__ We1, const float* __restrict__ be1,
    const float* __restrict__ We2, const float* __restrict__ be2,
    const float* __restrict__ Wx1, const float* __restrict__ bx1,
    const float* __restrict__ Wx2, const float* __restrict__ bx2,
    const float* __restrict__ Wh1, const float* __restrict__ bh1,
    const float* __restrict__ Wh2, const float* __restrict__ bh2,
    float* __restrict__ out)
{
  __shared__ __align__(16) float s_hst[16][64];
  __shared__ __align__(16) float s_u[16][64];
  __shared__ __align__(16) float s_miw[4][16][64];
  __shared__ __align__(16) unsigned int s_scr[4][2][64][4];  // per-wave, per-k-half, frag/lane
  __shared__ __align__(16) short8 s_af[16][64];   // c = 8*g + 2*mt + kk; g0=We2, g1=Wx1
  __shared__ float s_cvec[2][64];   // be2, bx1
  __shared__ float s_w1l[64];       // We1 dist row
  __shared__ float s_wx2[64];       // Wx2
  __shared__ float s_aggx[4][16], s_aggy[4][16], s_nn[4][16];
  __shared__ int s_flags[2];

  const int t  = threadIdx.x;
  const int l  = t & 63;
  const int w  = t >> 6;
  const int lg = l >> 4;
  const int jl = l & 15;
  const int base = blockIdx.x * NPB;

  if (t == 0) { s_flags[0] = 1; s_flags[1] = 1; }
  __syncthreads();
  {
    const unsigned int* mw = (const unsigned int*)mask8;
    unsigned int iok = 1, fok = 1;
    #pragma unroll
    for (int q = 0; q < 4; q++) {
      unsigned int v = mw[t * 4 + q];
      if (v > 1u) iok = 0;
      if (v != 0u && v != 0x3F800000u) fok = 0;
    }
    if (!iok) atomicAnd(&s_flags[0], 0);
    if (!fok) atomicAnd(&s_flags[1], 0);
  }
  {
    const f32x4* src = (const f32x4*)(h_st + (size_t)base * 64);
    f32x4* dst = (f32x4*)&s_hst[0][0];
    dst[t] = src[t];
    if (t < 64)        s_cvec[0][t] = be2[t];
    else if (t < 128)  s_cvec[1][t - 64] = bx1[t - 64];
    else if (t < 192)  s_w1l[t - 128] = We1[128 * 64 + (t - 128)];
    else               s_wx2[t - 192] = Wx2[t - 192];
  }
  // stage a2/a3 fragments into LDS: wave w stages combos 4w..4w+3
  #pragma unroll
  for (int ci = 0; ci < 4; ci++) {
    const int c  = 4 * w + ci;
    const int g  = c >> 3, mt = (c >> 1) & 3, kk = c & 1;
    const float* W = g ? Wx1 : We2;
    s_af[c][l] = ldfragT(W, 8 * lg + 32 * kk, 16 * mt + jl);
  }
  __syncthreads();
  const int mode = s_flags[0] ? 0 : (s_flags[1] ? 1 : 2);

  auto ldmask = [&](size_t idx) -> float {
    if (mode == 0)      return (((const int*)mask8)[idx] != 0) ? 1.f : 0.f;
    else if (mode == 1) return (((const float*)mask8)[idx] != 0.f) ? 1.f : 0.f;
    else                return (mask8[idx] != 0) ? 1.f : 0.f;
  };

  // D-quad (ht) of lane (jl,lg) -> scratch fragment slot (write side)
  const int sc_lgp_e = (lg >> 1);      // lgp = (2*ht + lg/2) & 3
  const int sc_m0    = 2 * (lg & 1);   // word pair within fragment

  // ---- U = be1 + h_st @ We1[0:64] ----
  {
    f32x4 uacc = {0.f, 0.f, 0.f, 0.f};
    #pragma unroll
    for (int kk = 0; kk < 2; kk++) {
      short8 au = ldfragT(We1, 8 * lg + 32 * kk, 16 * w + jl);
      f32x4 q0 = *(const f32x4*)&s_hst[jl][8 * lg + 32 * kk];
      f32x4 q1 = *(const f32x4*)&s_hst[jl][8 * lg + 32 * kk + 4];
      uacc = MFMA16(au, packb(q0, q1), uacc);
    }
    f32x4 b1v = *(const f32x4*)(be1 + 16 * w + 4 * lg);
    *(f32x4*)&s_u[jl][16 * w + 4 * lg] = uacc + b1v;
  }

  // ---- a1 (We1 lower) fragments in registers/AGPR ----
  short8 a1[4][2];
  #pragma unroll
  for (int mt = 0; mt < 4; mt++)
    #pragma unroll
    for (int kk = 0; kk < 2; kk++)
      a1[mt][kk] = ldfragT(We1 + 64 * 64, 8 * lg + 32 * kk, 16 * mt + jl);
  const float bx2s = bx2[0];

  // ---- initial prefetch (node 0) ----
  const float* hn_lane = h_neigh + ((size_t)base * 64 + 16 * w + jl) * 64 + 8 * lg;
  const size_t ro = (size_t)base * 64 + 16 * w + jl;
  f32x4 pf0 = *(const f32x4*)(hn_lane + 0);
  f32x4 pf1 = *(const f32x4*)(hn_lane + 4);
  f32x4 pf2 = *(const f32x4*)(hn_lane + 32);
  f32x4 pf3 = *(const f32x4*)(hn_lane + 36);
  f32x2 pre = *(const f32x2*)(rela + ro * 6);
  float pmf = ldmask(ro);
  __syncthreads();  // s_u + s_af ready

  // =========================== main loop ===========================
  #pragma unroll 1
  for (int nl = 0; nl < NPB; nl++) {
    // pack FIRST so pf* die before next prefetch issues
    const short8 b1k0 = packb(pf0, pf1);
    const short8 b1k1 = packb(pf2, pf3);
    const f32x2 rr = pre; const float mf = pmf;
    if (nl < NPB - 1) {
      const float* p = hn_lane + (size_t)(nl + 1) * 4096;
      pf0 = *(const f32x4*)(p + 0);  pf1 = *(const f32x4*)(p + 4);
      pf2 = *(const f32x4*)(p + 32); pf3 = *(const f32x4*)(p + 36);
      pre = *(const f32x2*)(rela + (ro + (size_t)(nl + 1) * 64) * 6);
      pmf = ldmask(ro + (size_t)(nl + 1) * 64);
    }
    const float d = sqrtf(rr[0] * rr[0] + rr[1] * rr[1]);

    float msum = mf;
    msum += __shfl_xor(msum, 1, 64); msum += __shfl_xor(msum, 2, 64);
    msum += __shfl_xor(msum, 4, 64); msum += __shfl_xor(msum, 8, 64);
    if (l == 0) s_nn[w][nl] = msum;

    // ---- GEMM1: E^T ----
    f32x4 acc[4];
    #pragma unroll
    for (int ht = 0; ht < 4; ht++) {
      const f32x4 wl = *(const f32x4*)&s_w1l[16 * ht + 4 * lg];
      acc[ht] = *(const f32x4*)&s_u[nl][16 * ht + 4 * lg] + d * wl;
      acc[ht] = MFMA16(a1[ht][0], b1k0, acc[ht]);
      acc[ht] = MFMA16(a1[ht][1], b1k1, acc[ht]);
    }
    #pragma unroll
    for (int ht = 0; ht < 4; ht++) {
      f32x4 e = silu4(acc[ht]);
      u32x2 wv; wv[0] = pk2(e[0], e[1]); wv[1] = pk2(e[2], e[3]);
      const int half = (4 * ht + lg) >> 3;
      const int lgp  = (2 * ht + sc_lgp_e) & 3;
      *(u32x2*)&s_scr[w][half][lgp * 16 + jl][sc_m0] = wv;
    }
    short8 b2k0 = *(const short8*)&s_scr[w][0][l][0];
    short8 b2k1 = *(const short8*)&s_scr[w][1][l][0];

    // ---- GEMM2: M^T (a2 fragments JIT from LDS) ----
    #pragma unroll
    for (int ht = 0; ht < 4; ht++) {
      const short8 f2k0 = s_af[2 * ht][l];
      const short8 f2k1 = s_af[2 * ht + 1][l];
      acc[ht] = *(const f32x4*)&s_cvec[0][16 * ht + 4 * lg];
      acc[ht] = MFMA16(f2k0, b2k0, acc[ht]);
      acc[ht] = MFMA16(f2k1, b2k1, acc[ht]);
    }
    #pragma unroll
    for (int ht = 0; ht < 4; ht++) {
      f32x4 m = silu4(acc[ht]) * mf;
      u32x2 wv; wv[0] = pk2(m[0], m[1]); wv[1] = pk2(m[2], m[3]);
      const int half = (4 * ht + lg) >> 3;
      const int lgp  = (2 * ht + sc_lgp_e) & 3;
      *(u32x2*)&s_scr[w][half][lgp * 16 + jl][sc_m0] = wv;
    }
    short8 b3k0 = *(const short8*)&s_scr[w][0][l][0];
    short8 b3k1 = *(const short8*)&s_scr[w][1][l][0];

    // ---- GEMM3: G^T (a3 fragments JIT from LDS) ----
    #pragma unroll
    for (int ht = 0; ht < 4; ht++) {
      const short8 f3k0 = s_af[8 + 2 * ht][l];
      const short8 f3k1 = s_af[8 + 2 * ht + 1][l];
      acc[ht] = *(const f32x4*)&s_cvec[1][16 * ht + 4 * lg];
      acc[ht] = MFMA16(f3k0, b3k0, acc[ht]);
      acc[ht] = MFMA16(f3k1, b3k1, acc[ht]);
    }

    // ---- m_i partial (reads m from scratch; overlaps GEMM3 MFMA latency) ----
    {
      const int hw = l & 31, jh = l >> 5;
      const int half = hw >> 4;          // h = 2*hw, 2*hw+1
      const int lgp  = (hw & 15) >> 2;
      const int m0   = hw & 3;
      const int rot  = hw >> 2;          // bank-rotation seed
      float pe = 0.f, po = 0.f;
      #pragma unroll
      for (int c = 0; c < 8; c++) {
        const int j = 8 * jh + ((c + rot) & 7);
        unsigned int v = s_scr[w][half][lgp * 16 + j][m0];
        pe += bfl(v); po += bfh(v);
      }
      pe += __shfl_xor(pe, 32, 64);
      po += __shfl_xor(po, 32, 64);
      if (l < 32) {
        f32x2 v2; v2[0] = pe; v2[1] = po;
        *(f32x2*)&s_miw[w][nl][2 * hw] = v2;
      }
    }

    // ---- gate ----
    float gg = 0.f;
    #pragma unroll
    for (int ht = 0; ht < 4; ht++) {
      const f32x4 wx = *(const f32x4*)&s_wx2[16 * ht + 4 * lg];
      f32x4 g = silu4(acc[ht]);
      gg += g[0] * wx[0] + g[1] * wx[1] + g[2] * wx[2] + g[3] * wx[3];
    }
    gg += __shfl_xor(gg, 16, 64);
    gg += __shfl_xor(gg, 32, 64);
    const float gate = gg + bx2s;

    float ax = rr[0] * gate, ay = rr[1] * gate;
    ax += __shfl_xor(ax, 1, 64); ay += __shfl_xor(ay, 1, 64);
    ax += __shfl_xor(ax, 2, 64); ay += __shfl_xor(ay, 2, 64);
    ax += __shfl_xor(ax, 4, 64); ay += __shfl_xor(ay, 4, 64);
    ax += __shfl_xor(ax, 8, 64); ay += __shfl_xor(ay, 8, 64);
    if (l == 0) { s_aggx[w][nl] = ax; s_aggy[w][nl] = ay; }
  }
  __syncthreads();

  // ---- x_new ----
  if (t < 32) {
    const int node = t >> 1, c = t & 1;
    const float nn = s_nn[0][node] + s_nn[1][node] + s_nn[2][node] + s_nn[3][node];
    const float ag = (c ? (s_aggy[0][node] + s_aggy[1][node] + s_aggy[2][node] + s_aggy[3][node])
                        : (s_aggx[0][node] + s_aggx[1][node] + s_aggx[2][node] + s_aggx[3][node]));
    out[(size_t)(base + node) * 2 + c] =
        ped[(size_t)(base + node) * 2 + c] + ag / (nn + 1e-6f);
  }

  // ---- f_h batched over 16 nodes ----
  {
    f32x4 hacc = *(const f32x4*)(bh1 + 16 * w + 4 * lg);
    #pragma unroll
    for (int kk = 0; kk < 4; kk++) {
      short8 ah = ldfragT(Wh1, 8 * lg + 32 * kk, 16 * w + jl);
      f32x4 q0, q1;
      if (kk < 2) {
        q0 = *(const f32x4*)&s_hst[jl][8 * lg + 32 * kk];
        q1 = *(const f32x4*)&s_hst[jl][8 * lg + 32 * kk + 4];
      } else {
        const int off = 8 * lg + 32 * (kk - 2);
        q0 = *(const f32x4*)&s_miw[0][jl][off]     + *(const f32x4*)&s_miw[1][jl][off]
           + *(const f32x4*)&s_miw[2][jl][off]     + *(const f32x4*)&s_miw[3][jl][off];
        q1 = *(const f32x4*)&s_miw[0][jl][off + 4] + *(const f32x4*)&s_miw[1][jl][off + 4]
           + *(const f32x4*)&s_miw[2][jl][off + 4] + *(const f32x4*)&s_miw[3][jl][off + 4];
      }
      hacc = MFMA16(ah, packb(q0, q1), hacc);
    }
    f32x4 h1 = silu4(hacc);
    u32x2 wv; wv[0] = pk2(h1[0], h1[1]); wv[1] = pk2(h1[2], h1[3]);
    const int half = (4 * w + lg) >> 3;          // "ht" = wave id here
    const int lgp  = (2 * w + sc_lgp_e) & 3;
    *(u32x2*)&s_scr[0][half][lgp * 16 + jl][sc_m0] = wv;
  }
  __syncthreads();
  {
    short8 hb0 = *(const short8*)&s_scr[0][0][l][0];
    short8 hb1 = *(const short8*)&s_scr[0][1][l][0];
    short8 aw0 = ldfragT(Wh2, 8 * lg,      16 * w + jl);
    short8 aw1 = ldfragT(Wh2, 8 * lg + 32, 16 * w + jl);
    f32x4 oacc = *(const f32x4*)(bh2 + 16 * w + 4 * lg);
    oacc = MFMA16(aw0, hb0, oacc);
    oacc = MFMA16(aw1, hb1, oacc);
    f32x4 res = oacc + *(const f32x4*)&s_hst[jl][16 * w + 4 * lg];
    *(f32x4*)(out + 32768 + (size_t)(base + jl) * 64 + 16 * w + 4 * lg) = res;
  }
}

extern "C" void kernel_launch(void* const* d_in, const int* in_sizes, int n_in,
                              void* d_out, int out_size, void* d_ws, size_t ws_size,
                              hipStream_t stream) {
  (void)in_sizes; (void)n_in; (void)out_size; (void)d_ws; (void)ws_size;
  const float* ped     = (const float*)d_in[0];
  const float* h_st    = (const float*)d_in[1];
  const float* h_neigh = (const float*)d_in[2];
  const float* rela    = (const float*)d_in[3];
  const unsigned char* mask = (const unsigned char*)d_in[4];
  const float* We1 = (const float*)d_in[5];  const float* be1 = (const float*)d_in[6];
  const float* We2 = (const float*)d_in[7];  const float* be2 = (const float*)d_in[8];
  const float* Wx1 = (const float*)d_in[9];  const float* bx1 = (const float*)d_in[10];
  const float* Wx2 = (const float*)d_in[11]; const float* bx2 = (const float*)d_in[12];
  const float* Wh1 = (const float*)d_in[13]; const float* bh1 = (const float*)d_in[14];
  const float* Wh2 = (const float*)d_in[15]; const float* bh2 = (const float*)d_in[16];

  hipLaunchKernelGGL(egnn_mfma, dim3(NBLK), dim3(256), 0, stream,
                     ped, h_st, h_neigh, rela, mask,
                     We1, be1, We2, be2, Wx1, bx1, Wx2, bx2,
                     Wh1, bh1, Wh2, bh2, (float*)d_out);
}